// Round 7
// baseline (306.117 us; speedup 1.0000x reference)
//
#include <hip/hip_runtime.h>
#include <hip/hip_bf16.h>

// Decoder block, round 7: GEMM v3 — A staged in LDS (2-parity ring, verified
// conflict-free swizzle), B fragments loaded DIRECTLY from global/L2 (weights
// are L2-resident), one __syncthreads per K-tile, setprio on MFMA clusters,
// XCD swizzle. Wo/ff2 write bf16; LN reads bf16 v-input. Attention unchanged.

#define D_MODEL 512
#define N_HEADS 8
#define D_HEAD 64
#define D_FF 2048
#define NROWS 16384   // B*T

typedef __bf16 bf16x8 __attribute__((ext_vector_type(8)));
typedef float f32x4 __attribute__((ext_vector_type(4)));

// XOR swizzle within a 128B-row tile: involution, bits 4-6 ^= row&7 (attn).
#define SWZ(x) ((x) ^ ((((x) >> 7) & 7) << 4))

static __device__ __forceinline__ ushort f2bf(float f) {
    union { float f; unsigned u; } v; v.f = f;
    unsigned r = v.u + 0x7fffu + ((v.u >> 16) & 1u);   // RNE
    return (ushort)(r >> 16);
}
static __device__ __forceinline__ unsigned pack2(float lo, float hi) {
    return (unsigned)f2bf(lo) | ((unsigned)f2bf(hi) << 16);
}
static __device__ __forceinline__ float bf2f(ushort u) {
    union { unsigned u; float f; } v; v.u = (unsigned)u << 16;
    return v.f;
}
static __device__ __forceinline__ void async16(const void* g, void* l) {
    __builtin_amdgcn_global_load_lds(
        (const __attribute__((address_space(1))) void*)g,
        (__attribute__((address_space(3))) void*)l, 16, 0, 0);
}

// ---------------------------------------------------------------- fp32 -> bf16
__global__ __launch_bounds__(256) void conv_bf_kernel(
    const float* __restrict__ src, ushort* __restrict__ dst, int n8)
{
    int i = blockIdx.x * 256 + threadIdx.x;
    if (i >= n8) return;
    const float4* s = (const float4*)src;
    float4 a = s[i * 2], b = s[i * 2 + 1];
    uint4 o;
    o.x = pack2(a.x, a.y); o.y = pack2(a.z, a.w);
    o.z = pack2(b.x, b.y); o.w = pack2(b.z, b.w);
    ((uint4*)dst)[i] = o;
}

// ---------------------------------------------------------------- transpose fp32[R][C] -> bf16[C][R]
static __device__ __forceinline__ void tile_transpose_body(
    const float* __restrict__ src, int srcldc, ushort* __restrict__ dst, int Rd,
    int r0, int c0)
{
    __shared__ float t[64][65];
    int tid = threadIdx.x;
    int lr = tid >> 4, lc4 = (tid & 15) * 4;
    #pragma unroll
    for (int i = 0; i < 4; ++i) {
        float4 v = *(const float4*)&src[(size_t)(r0 + lr + i * 16) * srcldc + c0 + lc4];
        t[lr + i * 16][lc4 + 0] = v.x;
        t[lr + i * 16][lc4 + 1] = v.y;
        t[lr + i * 16][lc4 + 2] = v.z;
        t[lr + i * 16][lc4 + 3] = v.w;
    }
    __syncthreads();
    int oc = tid >> 2, orr = (tid & 3) * 16;
    uint4 u0, u1;
    u0.x = pack2(t[orr + 0][oc],  t[orr + 1][oc]);
    u0.y = pack2(t[orr + 2][oc],  t[orr + 3][oc]);
    u0.z = pack2(t[orr + 4][oc],  t[orr + 5][oc]);
    u0.w = pack2(t[orr + 6][oc],  t[orr + 7][oc]);
    u1.x = pack2(t[orr + 8][oc],  t[orr + 9][oc]);
    u1.y = pack2(t[orr + 10][oc], t[orr + 11][oc]);
    u1.z = pack2(t[orr + 12][oc], t[orr + 13][oc]);
    u1.w = pack2(t[orr + 14][oc], t[orr + 15][oc]);
    ushort* d = dst + (size_t)(c0 + oc) * Rd + r0 + orr;
    *(uint4*)&d[0] = u0;
    *(uint4*)&d[8] = u1;
}

__global__ __launch_bounds__(256) void transpose_bf_kernel(
    const float* __restrict__ src, ushort* __restrict__ dst, int R, int C)
{
    tile_transpose_body(src, C, dst, R, blockIdx.y * 64, blockIdx.x * 64);
}

// Wq/Wk/Wv [H, D, dh] -> WpT bf16 [1536][512]; row = p*512 + h*64 + e, col = d.
__global__ __launch_bounds__(256) void qkv_pack_kernel(
    const float* __restrict__ Wq, const float* __restrict__ Wk,
    const float* __restrict__ Wv, ushort* __restrict__ WpT)
{
    int z = blockIdx.z;
    int p = z >> 3, h = z & 7;
    const float* src = ((p == 0) ? Wq : (p == 1) ? Wk : Wv) + (size_t)h * D_MODEL * D_HEAD;
    ushort* dst = WpT + (size_t)(p * D_MODEL + h * D_HEAD) * D_MODEL;
    tile_transpose_body(src, D_HEAD, dst, D_MODEL, blockIdx.y * 64, 0);
}

__global__ __launch_bounds__(256) void pack_bias_kernel(
    const float* __restrict__ bq, const float* __restrict__ bk,
    const float* __restrict__ bv, float* __restrict__ bp)
{
    int idx = blockIdx.x * 256 + threadIdx.x;
    if (idx >= 3 * D_MODEL) return;
    int p = idx / D_MODEL;
    int h = (idx % D_MODEL) / D_HEAD;
    int e = idx % D_HEAD;
    const float* bb = (p == 0) ? bq : (p == 1) ? bk : bv;
    bp[idx] = bb[h * D_HEAD + e];
}

// ---------------------------------------------------------------- GEMM v3
// C = A[M,K] @ BT[N,K]^T (+bias) (+relu). BM = QM*64, BN = NF*64, BK = 64.
// 512 thr = 8 waves (wm 0..1, wn 0..3); wave tile (QM*32) x (NF*16).
// A: LDS 2-parity ring of QM x 8KB quarters, staged via global_load_lds with
// the verified XOR swizzle (source pre-swizzle <-> swizzled read, both
// ((byte/16)^(row&7))<<4 within 128B rows). B: fragments loaded DIRECTLY from
// global (weights L2-resident; 16B/lane, 64B-line-exact). One __syncthreads
// per K-tile (vmcnt drain covers the A-DMA); no mid-tile barriers -> waves
// drift and self-pipeline; setprio favors MFMA-phase waves.
// OMODE: 0 = f32 out, 1 = bf16 out, 2 = QKV split (Qg/Kg natural, Vt transp).
template<int QM, int NF, int OMODE, bool RELU>
__global__ __launch_bounds__(512, 1) void gemmv3_kernel(
    const ushort* __restrict__ A, const ushort* __restrict__ BT,
    const float* __restrict__ bias, void* __restrict__ Cout,
    ushort* __restrict__ Qg, ushort* __restrict__ Kg, ushort* __restrict__ Vt,
    int N, int K, int nbx)
{
    extern __shared__ __align__(16) char smem[];   // 2 * QM * 8192

    const int tid = threadIdx.x;
    const int wid = tid >> 6, l = tid & 63;
    const int wm = wid >> 2, wn = wid & 3;

    // T1: bijective XCD swizzle (gridDim.x % 8 == 0 for all launches)
    const int cpx = gridDim.x >> 3;
    const int flat = blockIdx.x;
    const int swz = (flat & 7) * cpx + (flat >> 3);
    const int bx = swz % nbx, by = swz / nbx;
    const int m0 = by * (QM * 64), n0 = bx * (NF * 64);

    const char* Ac = (const char*)A;
    const char* Bc = (const char*)BT;
    const size_t K2 = (size_t)K * 2;
    const int T = K >> 6;

    // A staging geometry: QM x async16 per tile (1 quarter each), 1 load/thread
    const int srow = tid >> 3;
    const int ssw  = ((tid & 7) ^ (srow & 7)) << 4;

    // fragment geometry
    const int fr = l & 15, fq = l >> 4;
    const int rsw = (fr & 7) << 4;

    // B row pointers (per nf), direct-global
    const char* browp[NF];
    #pragma unroll
    for (int nf = 0; nf < NF; ++nf)
        browp[nf] = Bc + (size_t)(n0 + wn * (NF * 16) + nf * 16 + fr) * K2 + fq * 16;

    f32x4 acc[QM * 2][NF] = {};

    // prologue: stage tile 0; __syncthreads drains vmcnt
    #pragma unroll
    for (int q = 0; q < QM; ++q)
        async16(Ac + (size_t)(m0 + q * 64 + srow) * K2 + ssw,
                smem + q * 8192 + tid * 16);
    __syncthreads();

    for (int t = 0; t < T; ++t) {
        const char* par = smem + ((t & 1) ? QM * 8192 : 0);

        // B fragments for tile t (oldest vmem ops -> compiler's B-wait
        // does not drain the younger A-DMA below)
        bf16x8 bfr[NF][2];
        #pragma unroll
        for (int nf = 0; nf < NF; ++nf)
            #pragma unroll
            for (int ks = 0; ks < 2; ++ks)
                bfr[nf][ks] = *(const bf16x8*)(browp[nf] +
                    (size_t)t * 128 + ks * 64);

        // stage A(t+1) into the other parity
        if (t + 1 < T) {
            #pragma unroll
            for (int q = 0; q < QM; ++q)
                async16(Ac + (size_t)(m0 + q * 64 + srow) * K2 +
                            (size_t)(t + 1) * 128 + ssw,
                        smem + (((t + 1) & 1) ? QM * 8192 : 0) + q * 8192 +
                            tid * 16);
        }

        #pragma unroll
        for (int S = 0; S < 2; ++S) {
            bf16x8 af[QM][2];
            #pragma unroll
            for (int mi = 0; mi < QM; ++mi) {
                const int absrow = wm * (QM * 32) + (S * QM + mi) * 16;
                const int q = absrow >> 6, rin = absrow & 63;
                #pragma unroll
                for (int ks = 0; ks < 2; ++ks)
                    af[mi][ks] = *(const bf16x8*)(par + q * 8192 +
                        (rin + fr) * 128 + ((ks * 64 + fq * 16) ^ rsw));
            }
            __builtin_amdgcn_s_setprio(1);
            #pragma unroll
            for (int mi = 0; mi < QM; ++mi)
                #pragma unroll
                for (int nf = 0; nf < NF; ++nf) {
                    f32x4 a = acc[S * QM + mi][nf];
                    a = __builtin_amdgcn_mfma_f32_16x16x32_bf16(
                        af[mi][0], bfr[nf][0], a, 0, 0, 0);
                    a = __builtin_amdgcn_mfma_f32_16x16x32_bf16(
                        af[mi][1], bfr[nf][1], a, 0, 0, 0);
                    acc[S * QM + mi][nf] = a;
                }
            __builtin_amdgcn_s_setprio(0);
        }
        __syncthreads();   // drains A(t+1) DMA for all waves; parity flip safe
    }

    // epilogue: 16x16 C/D layout col = l&15, row = (l>>4)*4 + reg
    #pragma unroll
    for (int miA = 0; miA < QM * 2; ++miA) {
        const int r0 = m0 + wm * (QM * 32) + miA * 16 + fq * 4;
        #pragma unroll
        for (int nf = 0; nf < NF; ++nf) {
            const int c = n0 + wn * (NF * 16) + nf * 16 + fr;
            const float bvv = bias ? bias[c] : 0.f;
            float vv[4];
            #pragma unroll
            for (int reg = 0; reg < 4; ++reg) {
                float v = acc[miA][nf][reg] + bvv;
                if (RELU) v = fmaxf(v, 0.f);
                vv[reg] = v;
            }
            if (OMODE == 0) {
                #pragma unroll
                for (int reg = 0; reg < 4; ++reg)
                    ((float*)Cout)[(size_t)(r0 + reg) * N + c] = vv[reg];
            } else if (OMODE == 1) {
                #pragma unroll
                for (int reg = 0; reg < 4; ++reg)
                    ((ushort*)Cout)[(size_t)(r0 + reg) * N + c] = f2bf(vv[reg]);
            } else {
                const int p = n0 >> 9;             // uniform (n0 % 512 in {0,256})
                const int h = (c >> 6) & 7, e = c & 63;
                const int b = r0 >> 9, t0 = r0 & 511;
                const size_t bh = (size_t)(b * 8 + h);
                if (p == 2) {
                    uint2 pk;
                    pk.x = pack2(vv[0], vv[1]);
                    pk.y = pack2(vv[2], vv[3]);
                    *(uint2*)&Vt[bh * 32768 + (size_t)e * 512 + t0] = pk;
                } else {
                    ushort* dst = (p == 0 ? Qg : Kg) + bh * 32768 +
                                  (size_t)t0 * 64 + e;
                    dst[0]   = f2bf(vv[0]);
                    dst[64]  = f2bf(vv[1]);
                    dst[128] = f2bf(vv[2]);
                    dst[192] = f2bf(vv[3]);
                }
            }
        }
    }
}

// ---------------------------------------------------------------- MFMA attention
// (unchanged since round 3 -- passing)
__global__ __launch_bounds__(256) void attn_kernel(
    const ushort* __restrict__ Qg,   // [bh][t][e]
    const ushort* __restrict__ Kg,   // [bh][t][e]
    const ushort* __restrict__ Vt,   // [bh][e][t]
    ushort* __restrict__ O)          // [b*512+t][h*64+e]
{
    __shared__ __align__(16) char QP[8192];       // Q tile, then P strips
    __shared__ __align__(16) char KB[2][8192];
    __shared__ __align__(16) char VB[2][8192];

    const int bh = blockIdx.x, qb = blockIdx.y;
    const int tid = threadIdx.x;
    const int w = tid >> 6, l = tid & 63;

    const ushort* Qb = Qg + (size_t)bh * 32768;
    const ushort* Kb = Kg + (size_t)bh * 32768;
    const ushort* Vb = Vt + (size_t)bh * 32768;

    #pragma unroll
    for (int i = 0; i < 2; ++i) {
        int Xi = i * 4096 + tid * 16;
        int row = Xi >> 7;
        int sw = SWZ(Xi) & 127;
        async16((const char*)(Qb + (size_t)(qb * 64 + row) * 64) + sw, QP + Xi);
    }
    #define STAGEKV(kt, bb)                                                     \
        { _Pragma("unroll")                                                     \
          for (int i = 0; i < 2; ++i) {                                         \
              int Xi = i * 4096 + tid * 16;                                     \
              int row = Xi >> 7;                                                \
              int sw = SWZ(Xi) & 127;                                           \
              async16((const char*)(Kb + (size_t)((kt) * 64 + row) * 64) + sw,  \
                      KB[bb] + Xi);                                             \
              async16((const char*)(Vb + (size_t)row * 512 + (kt) * 64) + sw,   \
                      VB[bb] + Xi);                                             \
          } }
    STAGEKV(0, 0);
    __syncthreads();

    bf16x8 qf[2];
    {
        int qrow = w * 16 + (l & 15);
        #pragma unroll
        for (int ks = 0; ks < 2; ++ks) {
            int X = qrow * 128 + ks * 64 + (l >> 4) * 16;
            qf[ks] = *(const bf16x8*)(QP + SWZ(X));
        }
    }

    float mrow = -INFINITY, lrow = 0.f;
    f32x4 oacc[4] = {};

    for (int kt = 0; kt <= qb; ++kt) {
        int cur = kt & 1;
        if (kt < qb) STAGEKV(kt + 1, cur ^ 1);

        f32x4 sacc[4] = {};
        #pragma unroll
        for (int ks = 0; ks < 2; ++ks) {
            #pragma unroll
            for (int mi = 0; mi < 4; ++mi) {
                int X = (mi * 16 + (l & 15)) * 128 + ks * 64 + (l >> 4) * 16;
                bf16x8 kf = *(const bf16x8*)(KB[cur] + SWZ(X));
                sacc[mi] = __builtin_amdgcn_mfma_f32_16x16x32_bf16(
                    kf, qf[ks], sacc[mi], 0, 0, 0);
            }
        }

        float sv[16];
        float tmax = -INFINITY;
        const int qrow_t = w * 16 + (l & 15);
        #pragma unroll
        for (int mi = 0; mi < 4; ++mi)
            #pragma unroll
            for (int r = 0; r < 4; ++r) {
                float s = sacc[mi][r] * 0.125f;
                if (kt == qb) {
                    int key_l = mi * 16 + (l >> 4) * 4 + r;
                    if (key_l > qrow_t) s = -INFINITY;
                }
                sv[mi * 4 + r] = s;
                tmax = fmaxf(tmax, s);
            }
        tmax = fmaxf(tmax, __shfl_xor(tmax, 16));
        tmax = fmaxf(tmax, __shfl_xor(tmax, 32));
        float mnew = fmaxf(mrow, tmax);
        float corr = __expf(mrow - mnew);
        mrow = mnew;
        float psum = 0.f;
        #pragma unroll
        for (int i = 0; i < 16; ++i) { sv[i] = __expf(sv[i] - mnew); psum += sv[i]; }
        psum += __shfl_xor(psum, 16);
        psum += __shfl_xor(psum, 32);
        lrow = lrow * corr + psum;

        #pragma unroll
        for (int mi = 0; mi < 4; ++mi) {
            uint2 pk;
            pk.x = pack2(sv[mi * 4 + 0], sv[mi * 4 + 1]);
            pk.y = pack2(sv[mi * 4 + 2], sv[mi * 4 + 3]);
            int X = qrow_t * 128 + (mi * 16 + (l >> 4) * 4) * 2;
            *(uint2*)(QP + SWZ(X)) = pk;
        }

        #pragma unroll
        for (int r = 0; r < 4; ++r) {
            float cr = __shfl(corr, (l & 48) | ((l >> 4) * 4 + r));
            #pragma unroll
            for (int n = 0; n < 4; ++n) oacc[n][r] *= cr;
        }

        #pragma unroll
        for (int ks = 0; ks < 2; ++ks) {
            int Xa = qrow_t * 128 + ks * 64 + (l >> 4) * 16;
            bf16x8 pa = *(const bf16x8*)(QP + SWZ(Xa));
            #pragma unroll
            for (int n = 0; n < 4; ++n) {
                int Xb = (n * 16 + (l & 15)) * 128 + ks * 64 + (l >> 4) * 16;
                bf16x8 vb = *(const bf16x8*)(VB[cur] + SWZ(Xb));
                oacc[n] = __builtin_amdgcn_mfma_f32_16x16x32_bf16(
                    pa, vb, oacc[n], 0, 0, 0);
            }
        }
        __syncthreads();
    }

    float linv = 1.0f / lrow;
    const int b_ = bh >> 3, h_ = bh & 7;
    #pragma unroll
    for (int r = 0; r < 4; ++r) {
        float li = __shfl(linv, (l & 48) | ((l >> 4) * 4 + r));
        int trow = qb * 64 + w * 16 + (l >> 4) * 4 + r;
        size_t obase = ((size_t)b_ * 512 + trow) * 512 + h_ * 64 + (l & 15);
        #pragma unroll
        for (int n = 0; n < 4; ++n)
            O[obase + n * 16] = f2bf(oacc[n][r] * li);
    }
}

// ---------------------------------------------------------------- LN + residual
// v (the layernormed value) is bf16; residual/res and out are fp32.
// lane owns cols lane*8 .. lane*8+7.
template<bool WBF>
__global__ __launch_bounds__(256) void ln_res_kernel(
    const ushort* __restrict__ v, const float* __restrict__ res,
    const float* __restrict__ g, const float* __restrict__ bb,
    float* __restrict__ out, ushort* __restrict__ out_bf)
{
    int row  = blockIdx.x * 4 + (threadIdx.x >> 6);
    int lane = threadIdx.x & 63;
    const int c0 = lane * 8;

    uint4 vb = *(const uint4*)&v[(size_t)row * D_MODEL + c0];
    float f[8];
    f[0] = bf2f((ushort)(vb.x & 0xffff)); f[1] = bf2f((ushort)(vb.x >> 16));
    f[2] = bf2f((ushort)(vb.y & 0xffff)); f[3] = bf2f((ushort)(vb.y >> 16));
    f[4] = bf2f((ushort)(vb.z & 0xffff)); f[5] = bf2f((ushort)(vb.z >> 16));
    f[6] = bf2f((ushort)(vb.w & 0xffff)); f[7] = bf2f((ushort)(vb.w >> 16));

    float sum = 0.f, sq = 0.f;
    #pragma unroll
    for (int i = 0; i < 8; ++i) { sum += f[i]; sq += f[i] * f[i]; }
    #pragma unroll
    for (int o = 1; o < 64; o <<= 1) {
        sum += __shfl_xor(sum, o);
        sq  += __shfl_xor(sq, o);
    }
    float mu   = sum * (1.f / 512.f);
    float var  = sq * (1.f / 512.f) - mu * mu;
    float rstd = rsqrtf(var + 1e-5f);

    float4 r0 = *(const float4*)&res[(size_t)row * D_MODEL + c0];
    float4 r1 = *(const float4*)&res[(size_t)row * D_MODEL + c0 + 4];
    float4 g0 = *(const float4*)&g[c0],  g1 = *(const float4*)&g[c0 + 4];
    float4 b0 = *(const float4*)&bb[c0], b1 = *(const float4*)&bb[c0 + 4];

    float o8[8];
    o8[0] = r0.x + (f[0] - mu) * rstd * g0.x + b0.x;
    o8[1] = r0.y + (f[1] - mu) * rstd * g0.y + b0.y;
    o8[2] = r0.z + (f[2] - mu) * rstd * g0.z + b0.z;
    o8[3] = r0.w + (f[3] - mu) * rstd * g0.w + b0.w;
    o8[4] = r1.x + (f[4] - mu) * rstd * g1.x + b1.x;
    o8[5] = r1.y + (f[5] - mu) * rstd * g1.y + b1.y;
    o8[6] = r1.z + (f[6] - mu) * rstd * g1.z + b1.z;
    o8[7] = r1.w + (f[7] - mu) * rstd * g1.w + b1.w;

    float4* op = (float4*)&out[(size_t)row * D_MODEL + c0];
    op[0] = make_float4(o8[0], o8[1], o8[2], o8[3]);
    op[1] = make_float4(o8[4], o8[5], o8[6], o8[7]);
    if (WBF) {
        uint4 pk;
        pk.x = pack2(o8[0], o8[1]); pk.y = pack2(o8[2], o8[3]);
        pk.z = pack2(o8[4], o8[5]); pk.w = pack2(o8[6], o8[7]);
        *(uint4*)&out_bf[(size_t)row * D_MODEL + c0] = pk;
    }
}

// ---------------------------------------------------------------- launch
extern "C" void kernel_launch(void* const* d_in, const int* in_sizes, int n_in,
                              void* d_out, int out_size, void* d_ws, size_t ws_size,
                              hipStream_t stream)
{
    const float* x     = (const float*)d_in[0];
    const float* Wq    = (const float*)d_in[1];
    const float* bq    = (const float*)d_in[2];
    const float* Wk    = (const float*)d_in[3];
    const float* bk    = (const float*)d_in[4];
    const float* Wv    = (const float*)d_in[5];
    const float* bv    = (const float*)d_in[6];
    const float* Wo    = (const float*)d_in[7];
    const float* bo    = (const float*)d_in[8];
    const float* ln1_g = (const float*)d_in[9];
    const float* ln1_b = (const float*)d_in[10];
    const float* W1    = (const float*)d_in[11];
    const float* b1    = (const float*)d_in[12];
    const float* W2    = (const float*)d_in[13];
    const float* b2    = (const float*)d_in[14];
    const float* ln2_g = (const float*)d_in[15];
    const float* ln2_b = (const float*)d_in[16];

    float* ws = (float*)d_ws;
    ushort* Qg      = (ushort*)(ws);               // 8,388,608 us
    ushort* Kg      = (ushort*)(ws + 4194304);     // 8,388,608 us
    ushort* Vt      = (ushort*)(ws + 8388608);     // 8,388,608 us
    ushort* O_bf    = (ushort*)(ws + 12582912);    // 8,388,608 us
    ushort* attn_bf = (ushort*)(ws + 16777216);    // 8,388,608 us
    float*  out1    = ws + 20971520;               // 8,388,608 f32
    ushort* out1_bf = (ushort*)(ws + 29360128);    // 8,388,608 us
    ushort* x_bf    = (ushort*)(ws + 33554432);    // 8,388,608 us
    ushort* ff2_bf  = (ushort*)(ws + 37748736);    // 8,388,608 us
    ushort* WpT     = (ushort*)(ws + 41943040);    // 786,432 us
    ushort* WoT     = (ushort*)(ws + 42336256);    // 262,144 us
    ushort* W1T     = (ushort*)(ws + 42467328);    // 1,048,576 us
    ushort* W2T     = (ushort*)(ws + 42991616);    // 1,048,576 us
    float*  bp      = ws + 43515904;               // 1,536 f32
    ushort* ff1_bf  = (ushort*)ws;                 // 33,554,432 us (aliases Qg..O_bf)

    // allow 64KB dynamic LDS (idempotent; ignore errors)
    (void)hipFuncSetAttribute(
        reinterpret_cast<const void*>(&gemmv3_kernel<4, 4, 2, false>),
        hipFuncAttributeMaxDynamicSharedMemorySize, 65536);
    (void)hipFuncSetAttribute(
        reinterpret_cast<const void*>(&gemmv3_kernel<4, 4, 1, true>),
        hipFuncAttributeMaxDynamicSharedMemorySize, 65536);
    (void)hipFuncSetAttribute(
        reinterpret_cast<const void*>(&gemmv3_kernel<2, 2, 1, false>),
        hipFuncAttributeMaxDynamicSharedMemorySize, 32768);

    conv_bf_kernel<<<dim3(4096), 256, 0, stream>>>(x, x_bf, NROWS * D_MODEL / 8);
    qkv_pack_kernel<<<dim3(1, 8, 24), 256, 0, stream>>>(Wq, Wk, Wv, WpT);
    transpose_bf_kernel<<<dim3(8, 8), 256, 0, stream>>>(Wo, WoT, 512, 512);
    transpose_bf_kernel<<<dim3(32, 8), 256, 0, stream>>>(W1, W1T, 512, 2048);
    transpose_bf_kernel<<<dim3(8, 32), 256, 0, stream>>>(W2, W2T, 2048, 512);
    pack_bias_kernel<<<dim3(6), 256, 0, stream>>>(bq, bk, bv, bp);

    // QKV: x @ Wp + bp -> Qg/Kg natural, Vt transposed. QM4/NF4, grid 64*6=384
    gemmv3_kernel<4, 4, 2, false><<<dim3(384), 512, 65536, stream>>>(
        x_bf, WpT, bp, nullptr, Qg, Kg, Vt, 1536, 512, 6);

    // attention -> O_bf
    attn_kernel<<<dim3(256, 8), 256, 0, stream>>>(Qg, Kg, Vt, O_bf);

    // attn = O @ Wo + bo -> bf16. QM2/NF2 (128x128), grid 128*4=512
    gemmv3_kernel<2, 2, 1, false><<<dim3(512), 512, 32768, stream>>>(
        O_bf, WoT, bo, attn_bf, nullptr, nullptr, nullptr, 512, 512, 4);

    // out1 = x + LN(attn); + bf16 copy
    ln_res_kernel<true><<<dim3(NROWS / 4), 256, 0, stream>>>(
        attn_bf, x, ln1_g, ln1_b, out1, out1_bf);

    // ff1 = relu(out1 @ W1 + b1) -> bf16. QM4/NF4, grid 64*8=512
    gemmv3_kernel<4, 4, 1, true><<<dim3(512), 512, 65536, stream>>>(
        out1_bf, W1T, b1, ff1_bf, nullptr, nullptr, nullptr, 2048, 512, 8);

    // ff2 = ff1 @ W2 + b2 -> bf16. QM2/NF2, grid 128*4=512, T=32
    gemmv3_kernel<2, 2, 1, false><<<dim3(512), 512, 32768, stream>>>(
        ff1_bf, W2T, b2, ff2_bf, nullptr, nullptr, nullptr, 512, 2048, 4);

    // out = out1 + LN(ff2)
    ln_res_kernel<false><<<dim3(NROWS / 4), 256, 0, stream>>>(
        ff2_bf, out1, ln2_g, ln2_b, (float*)d_out, nullptr);
}

// Round 9
// 211.022 us; speedup vs baseline: 1.4506x; 1.4506x over previous
//
#include <hip/hip_runtime.h>
#include <hip/hip_bf16.h>

// Decoder block, round 9: round-8 pipeline with the GEMM staging RACE FIXED.
// Race-free 2-phase ledger: STAGE(t+1) -> compute(t) -> vmcnt(0) -> s_barrier
// (wait BEFORE barrier; per-wave vmcnt + barrier => all waves' DMAs landed).
// Keeps: fused prep, bf16 Wo/ff2 outputs, bf16-input LN, attention (r3).

#define D_MODEL 512
#define N_HEADS 8
#define D_HEAD 64
#define D_FF 2048
#define NROWS 16384   // B*T

typedef __bf16 bf16x8 __attribute__((ext_vector_type(8)));
typedef float f32x4 __attribute__((ext_vector_type(4)));
typedef float f32x16 __attribute__((ext_vector_type(16)));

// XOR swizzle within a 128B-row tile: involution, bits 4-6 ^= row&7 (attn).
#define SWZ(x) ((x) ^ ((((x) >> 7) & 7) << 4))

static __device__ __forceinline__ ushort f2bf(float f) {
    union { float f; unsigned u; } v; v.f = f;
    unsigned r = v.u + 0x7fffu + ((v.u >> 16) & 1u);   // RNE
    return (ushort)(r >> 16);
}
static __device__ __forceinline__ unsigned pack2(float lo, float hi) {
    return (unsigned)f2bf(lo) | ((unsigned)f2bf(hi) << 16);
}
static __device__ __forceinline__ float bf2f(ushort u) {
    union { unsigned u; float f; } v; v.u = (unsigned)u << 16;
    return v.f;
}
static __device__ __forceinline__ void async16(const void* g, void* l) {
    __builtin_amdgcn_global_load_lds(
        (const __attribute__((address_space(1))) void*)g,
        (__attribute__((address_space(3))) void*)l, 16, 0, 0);
}

// ---------------------------------------------------------------- fused prep
// blocks [0,4096): x fp32 -> bf16
// [4096,4288): Wq/Wk/Wv [H,D,dh] -> WpT [1536][512]
// [4288,4352): Wo^T -> WoT [512][512]
// [4352,4608): W1^T -> W1T [2048][512]
// [4608,4864): W2^T -> W2T [512][2048]
// [4864,4870): qkv bias pack
static __device__ __forceinline__ void tile_transpose_body(
    const float* __restrict__ src, int srcldc, ushort* __restrict__ dst, int Rd,
    int r0, int c0)
{
    __shared__ float t[64][65];
    int tid = threadIdx.x;
    int lr = tid >> 4, lc4 = (tid & 15) * 4;
    #pragma unroll
    for (int i = 0; i < 4; ++i) {
        float4 v = *(const float4*)&src[(size_t)(r0 + lr + i * 16) * srcldc + c0 + lc4];
        t[lr + i * 16][lc4 + 0] = v.x;
        t[lr + i * 16][lc4 + 1] = v.y;
        t[lr + i * 16][lc4 + 2] = v.z;
        t[lr + i * 16][lc4 + 3] = v.w;
    }
    __syncthreads();
    int oc = tid >> 2, orr = (tid & 3) * 16;
    uint4 u0, u1;
    u0.x = pack2(t[orr + 0][oc],  t[orr + 1][oc]);
    u0.y = pack2(t[orr + 2][oc],  t[orr + 3][oc]);
    u0.z = pack2(t[orr + 4][oc],  t[orr + 5][oc]);
    u0.w = pack2(t[orr + 6][oc],  t[orr + 7][oc]);
    u1.x = pack2(t[orr + 8][oc],  t[orr + 9][oc]);
    u1.y = pack2(t[orr + 10][oc], t[orr + 11][oc]);
    u1.z = pack2(t[orr + 12][oc], t[orr + 13][oc]);
    u1.w = pack2(t[orr + 14][oc], t[orr + 15][oc]);
    ushort* d = dst + (size_t)(c0 + oc) * Rd + r0 + orr;
    *(uint4*)&d[0] = u0;
    *(uint4*)&d[8] = u1;
}

__global__ __launch_bounds__(256) void prep_kernel(
    const float* __restrict__ x, ushort* __restrict__ x_bf,
    const float* __restrict__ Wq, const float* __restrict__ Wk,
    const float* __restrict__ Wv, ushort* __restrict__ WpT,
    const float* __restrict__ Wo, ushort* __restrict__ WoT,
    const float* __restrict__ W1, ushort* __restrict__ W1T,
    const float* __restrict__ W2, ushort* __restrict__ W2T,
    const float* __restrict__ bq, const float* __restrict__ bk,
    const float* __restrict__ bv, float* __restrict__ bp)
{
    const int blk = blockIdx.x;
    const int tid = threadIdx.x;
    if (blk < 4096) {
        int i = blk * 256 + tid;                  // over 1,048,576 uint4s
        const float4* s = (const float4*)x;
        float4 a = s[i * 2], b = s[i * 2 + 1];
        uint4 o;
        o.x = pack2(a.x, a.y); o.y = pack2(a.z, a.w);
        o.z = pack2(b.x, b.y); o.w = pack2(b.z, b.w);
        ((uint4*)x_bf)[i] = o;
    } else if (blk < 4288) {
        int idx = blk - 4096;                     // 192: z=idx>>3 (p,h), y=idx&7
        int z = idx >> 3, y = idx & 7;
        int p = z >> 3, h = z & 7;
        const float* src = ((p == 0) ? Wq : (p == 1) ? Wk : Wv) +
                           (size_t)h * D_MODEL * D_HEAD;
        ushort* dst = WpT + (size_t)(p * D_MODEL + h * D_HEAD) * D_MODEL;
        tile_transpose_body(src, D_HEAD, dst, D_MODEL, y * 64, 0);
    } else if (blk < 4352) {
        int idx = blk - 4288;                     // 64: 8x8
        tile_transpose_body(Wo, 512, WoT, 512, (idx >> 3) * 64, (idx & 7) * 64);
    } else if (blk < 4608) {
        int idx = blk - 4352;                     // 256: 8r x 32c
        tile_transpose_body(W1, 2048, W1T, 512, (idx >> 5) * 64, (idx & 31) * 64);
    } else if (blk < 4864) {
        int idx = blk - 4608;                     // 256: 32r x 8c
        tile_transpose_body(W2, 512, W2T, 2048, (idx >> 3) * 64, (idx & 7) * 64);
    } else {
        int gid = (blk - 4864) * 256 + tid;       // over 1536
        if (gid < 3 * D_MODEL) {
            int p = gid / D_MODEL;
            int h = (gid % D_MODEL) / D_HEAD;
            int e = gid % D_HEAD;
            const float* bb = (p == 0) ? bq : (p == 1) ? bk : bv;
            bp[gid] = bb[h * D_HEAD + e];
        }
    }
}

// ---------------------------------------------------------------- bf16 MFMA GEMM
// C = A[M,K] @ BT[N,K]^T (+bias) (+relu). BM=256, BN=128, BK=64.
// 512 threads = 8 waves (4 wr x 2 wc), wave 64x64 via 2x2 mfma_32x32x16.
// LDS: 2 bufs x (A 32KB + B 16KB) = 96KB. RACE-FREE ledger:
//   prologue: STAGE(0); vmcnt(0); barrier
//   iter t:   STAGE(t+1) -> compute(t) -> vmcnt(0) -> barrier
// vmcnt(0) BEFORE the barrier: each wave drains its own DMAs, so after the
// barrier ALL waves' tile-(t+1) data is in LDS; the same barrier orders all
// compute(t) reads before iter-(t+1)'s overwrite of parity (t+1)&1.
// OMODE: 1 = bf16 out, 2 = QKV split (Qg/Kg natural, Vt transposed).
template<int OMODE, bool RELU>
__global__ __launch_bounds__(512, 1) void gemm_bf16_kernel(
    const ushort* __restrict__ A, const ushort* __restrict__ BT,
    const float* __restrict__ bias, void* __restrict__ Cout,
    ushort* __restrict__ Qg, ushort* __restrict__ Kg, ushort* __restrict__ Vt,
    int M, int N, int K, int nbx)
{
    extern __shared__ __align__(16) char smem[];   // 2 x 49152

    const int tid = threadIdx.x;
    const int wid = tid >> 6, l = tid & 63;
    const int wr = wid >> 1, wc = wid & 1;

    // T1: bijective XCD swizzle (gridDim.x % 8 == 0 for all our launches)
    const int cpx = gridDim.x >> 3;
    const int flat = blockIdx.x;
    const int swz = (flat & 7) * cpx + (flat >> 3);
    const int bx = swz % nbx, by = swz / nbx;
    const int m0 = by * 256, n0 = bx * 128;

    const int srow = tid >> 3;           // 0..63 per issue
    const int sbyte = (tid & 7) * 16;
    const int ssw = sbyte ^ ((srow & 7) << 4);

    #define STAGE(t)                                                          \
    {                                                                         \
        const int kk_ = (t) * 64;                                             \
        char* dst_ = smem + ((t) & 1) * 49152;                                \
        _Pragma("unroll")                                                     \
        for (int i = 0; i < 4; ++i)                                           \
            async16((const char*)(A + (size_t)(m0 + i * 64 + srow) * K + kk_) \
                        + ssw,                                                \
                    dst_ + i * 8192 + tid * 16);                              \
        _Pragma("unroll")                                                     \
        for (int i = 0; i < 2; ++i)                                           \
            async16((const char*)(BT + (size_t)(n0 + i * 64 + srow) * K + kk_)\
                        + ssw,                                                \
                    dst_ + 32768 + i * 8192 + tid * 16);                      \
    }

    const int fl = l & 31, fh = l >> 5;
    const int frsw = (fl & 7) << 4;

    f32x16 acc[2][2] = {};

    const int T = K >> 6;
    STAGE(0);
    asm volatile("s_waitcnt vmcnt(0)" ::: "memory");
    __builtin_amdgcn_s_barrier();
    __builtin_amdgcn_sched_barrier(0);

    for (int t = 0; t < T; ++t) {
        if (t + 1 < T) STAGE(t + 1);   // flies under compute(t)

        const char* bufA = smem + (t & 1) * 49152;
        const char* bufB = bufA + 32768;
        #pragma unroll
        for (int ks = 0; ks < 4; ++ks) {
            const int kb = ((ks * 32 + fh * 16) ^ frsw);
            bf16x8 af[2], bfv[2];
            #pragma unroll
            for (int mi = 0; mi < 2; ++mi)
                af[mi] = *(const bf16x8*)(bufA +
                    (wr * 64 + mi * 32 + fl) * 128 + kb);
            #pragma unroll
            for (int ni = 0; ni < 2; ++ni)
                bfv[ni] = *(const bf16x8*)(bufB +
                    (wc * 64 + ni * 32 + fl) * 128 + kb);
            #pragma unroll
            for (int mi = 0; mi < 2; ++mi)
                #pragma unroll
                for (int ni = 0; ni < 2; ++ni)
                    acc[mi][ni] = __builtin_amdgcn_mfma_f32_32x32x16_bf16(
                        af[mi], bfv[ni], acc[mi][ni], 0, 0, 0);
        }

        if (t + 1 < T) {
            asm volatile("s_waitcnt vmcnt(0)" ::: "memory");  // own t+1 landed
            __builtin_amdgcn_s_barrier();   // all waves: compute(t) done + t+1 in LDS
            __builtin_amdgcn_sched_barrier(0);
        }
    }
    #undef STAGE

    // epilogue: 32x32 C/D layout col = l&31, row = (reg&3) + 8*(reg>>2) + 4*(l>>5)
    #pragma unroll
    for (int ni = 0; ni < 2; ++ni) {
        const int c = n0 + wc * 64 + ni * 32 + fl;
        const float bvv = bias ? bias[c] : 0.f;
        #pragma unroll
        for (int mi = 0; mi < 2; ++mi) {
            const int rbase = m0 + wr * 64 + mi * 32 + (fh << 2);
            float vv[16];
            #pragma unroll
            for (int reg = 0; reg < 16; ++reg) {
                float v = acc[mi][ni][reg] + bvv;
                if (RELU) v = fmaxf(v, 0.f);
                vv[reg] = v;
            }
            if (OMODE == 1) {
                #pragma unroll
                for (int reg = 0; reg < 16; ++reg) {
                    int r = rbase + (reg & 3) + ((reg >> 2) << 3);
                    ((ushort*)Cout)[(size_t)r * N + c] = f2bf(vv[reg]);
                }
            } else {
                const int p = n0 >> 9;            // uniform per block
                const int h = (c >> 6) & 7, e = c & 63;
                #pragma unroll
                for (int q = 0; q < 4; ++q) {
                    int r0 = rbase + (q << 3);    // rows r0..r0+3 (same b)
                    int b = r0 >> 9, t0 = r0 & 511;
                    size_t bh = (size_t)(b * 8 + h);
                    if (p == 2) {
                        uint2 pk;
                        pk.x = pack2(vv[q * 4 + 0], vv[q * 4 + 1]);
                        pk.y = pack2(vv[q * 4 + 2], vv[q * 4 + 3]);
                        *(uint2*)&Vt[bh * 32768 + (size_t)e * 512 + t0] = pk;
                    } else {
                        ushort* dst = (p == 0 ? Qg : Kg) + bh * 32768 +
                                      (size_t)t0 * 64 + e;
                        dst[0]   = f2bf(vv[q * 4 + 0]);
                        dst[64]  = f2bf(vv[q * 4 + 1]);
                        dst[128] = f2bf(vv[q * 4 + 2]);
                        dst[192] = f2bf(vv[q * 4 + 3]);
                    }
                }
            }
        }
    }
}

// ---------------------------------------------------------------- MFMA attention
// (unchanged since round 3 -- passing; __syncthreads = drain+barrier, race-free)
__global__ __launch_bounds__(256) void attn_kernel(
    const ushort* __restrict__ Qg,   // [bh][t][e]
    const ushort* __restrict__ Kg,   // [bh][t][e]
    const ushort* __restrict__ Vt,   // [bh][e][t]
    ushort* __restrict__ O)          // [b*512+t][h*64+e]
{
    __shared__ __align__(16) char QP[8192];       // Q tile, then P strips
    __shared__ __align__(16) char KB[2][8192];
    __shared__ __align__(16) char VB[2][8192];

    const int bh = blockIdx.x, qb = blockIdx.y;
    const int tid = threadIdx.x;
    const int w = tid >> 6, l = tid & 63;

    const ushort* Qb = Qg + (size_t)bh * 32768;
    const ushort* Kb = Kg + (size_t)bh * 32768;
    const ushort* Vb = Vt + (size_t)bh * 32768;

    #pragma unroll
    for (int i = 0; i < 2; ++i) {
        int Xi = i * 4096 + tid * 16;
        int row = Xi >> 7;
        int sw = SWZ(Xi) & 127;
        async16((const char*)(Qb + (size_t)(qb * 64 + row) * 64) + sw, QP + Xi);
    }
    #define STAGEKV(kt, bb)                                                     \
        { _Pragma("unroll")                                                     \
          for (int i = 0; i < 2; ++i) {                                         \
              int Xi = i * 4096 + tid * 16;                                     \
              int row = Xi >> 7;                                                \
              int sw = SWZ(Xi) & 127;                                           \
              async16((const char*)(Kb + (size_t)((kt) * 64 + row) * 64) + sw,  \
                      KB[bb] + Xi);                                             \
              async16((const char*)(Vb + (size_t)row * 512 + (kt) * 64) + sw,   \
                      VB[bb] + Xi);                                             \
          } }
    STAGEKV(0, 0);
    __syncthreads();

    bf16x8 qf[2];
    {
        int qrow = w * 16 + (l & 15);
        #pragma unroll
        for (int ks = 0; ks < 2; ++ks) {
            int X = qrow * 128 + ks * 64 + (l >> 4) * 16;
            qf[ks] = *(const bf16x8*)(QP + SWZ(X));
        }
    }

    float mrow = -INFINITY, lrow = 0.f;
    f32x4 oacc[4] = {};

    for (int kt = 0; kt <= qb; ++kt) {
        int cur = kt & 1;
        if (kt < qb) STAGEKV(kt + 1, cur ^ 1);

        f32x4 sacc[4] = {};
        #pragma unroll
        for (int ks = 0; ks < 2; ++ks) {
            #pragma unroll
            for (int mi = 0; mi < 4; ++mi) {
                int X = (mi * 16 + (l & 15)) * 128 + ks * 64 + (l >> 4) * 16;
                bf16x8 kf = *(const bf16x8*)(KB[cur] + SWZ(X));
                sacc[mi] = __builtin_amdgcn_mfma_f32_16x16x32_bf16(
                    kf, qf[ks], sacc[mi], 0, 0, 0);
            }
        }

        float sv[16];
        float tmax = -INFINITY;
        const int qrow_t = w * 16 + (l & 15);
        #pragma unroll
        for (int mi = 0; mi < 4; ++mi)
            #pragma unroll
            for (int r = 0; r < 4; ++r) {
                float s = sacc[mi][r] * 0.125f;
                if (kt == qb) {
                    int key_l = mi * 16 + (l >> 4) * 4 + r;
                    if (key_l > qrow_t) s = -INFINITY;
                }
                sv[mi * 4 + r] = s;
                tmax = fmaxf(tmax, s);
            }
        tmax = fmaxf(tmax, __shfl_xor(tmax, 16));
        tmax = fmaxf(tmax, __shfl_xor(tmax, 32));
        float mnew = fmaxf(mrow, tmax);
        float corr = __expf(mrow - mnew);
        mrow = mnew;
        float psum = 0.f;
        #pragma unroll
        for (int i = 0; i < 16; ++i) { sv[i] = __expf(sv[i] - mnew); psum += sv[i]; }
        psum += __shfl_xor(psum, 16);
        psum += __shfl_xor(psum, 32);
        lrow = lrow * corr + psum;

        #pragma unroll
        for (int mi = 0; mi < 4; ++mi) {
            uint2 pk;
            pk.x = pack2(sv[mi * 4 + 0], sv[mi * 4 + 1]);
            pk.y = pack2(sv[mi * 4 + 2], sv[mi * 4 + 3]);
            int X = qrow_t * 128 + (mi * 16 + (l >> 4) * 4) * 2;
            *(uint2*)(QP + SWZ(X)) = pk;
        }

        #pragma unroll
        for (int r = 0; r < 4; ++r) {
            float cr = __shfl(corr, (l & 48) | ((l >> 4) * 4 + r));
            #pragma unroll
            for (int n = 0; n < 4; ++n) oacc[n][r] *= cr;
        }

        #pragma unroll
        for (int ks = 0; ks < 2; ++ks) {
            int Xa = qrow_t * 128 + ks * 64 + (l >> 4) * 16;
            bf16x8 pa = *(const bf16x8*)(QP + SWZ(Xa));
            #pragma unroll
            for (int n = 0; n < 4; ++n) {
                int Xb = (n * 16 + (l & 15)) * 128 + ks * 64 + (l >> 4) * 16;
                bf16x8 vb = *(const bf16x8*)(VB[cur] + SWZ(Xb));
                oacc[n] = __builtin_amdgcn_mfma_f32_16x16x32_bf16(
                    pa, vb, oacc[n], 0, 0, 0);
            }
        }
        __syncthreads();
    }

    float linv = 1.0f / lrow;
    const int b_ = bh >> 3, h_ = bh & 7;
    #pragma unroll
    for (int r = 0; r < 4; ++r) {
        float li = __shfl(linv, (l & 48) | ((l >> 4) * 4 + r));
        int trow = qb * 64 + w * 16 + (l >> 4) * 4 + r;
        size_t obase = ((size_t)b_ * 512 + trow) * 512 + h_ * 64 + (l & 15);
        #pragma unroll
        for (int n = 0; n < 4; ++n)
            O[obase + n * 16] = f2bf(oacc[n][r] * li);
    }
}

// ---------------------------------------------------------------- LN + residual
// v (the layernormed value) is bf16; res and out are fp32.
template<bool WBF>
__global__ __launch_bounds__(256) void ln_res_kernel(
    const ushort* __restrict__ v, const float* __restrict__ res,
    const float* __restrict__ g, const float* __restrict__ bb,
    float* __restrict__ out, ushort* __restrict__ out_bf)
{
    int row  = blockIdx.x * 4 + (threadIdx.x >> 6);
    int lane = threadIdx.x & 63;
    const int c0 = lane * 8;

    uint4 vb = *(const uint4*)&v[(size_t)row * D_MODEL + c0];
    float f[8];
    f[0] = bf2f((ushort)(vb.x & 0xffff)); f[1] = bf2f((ushort)(vb.x >> 16));
    f[2] = bf2f((ushort)(vb.y & 0xffff)); f[3] = bf2f((ushort)(vb.y >> 16));
    f[4] = bf2f((ushort)(vb.z & 0xffff)); f[5] = bf2f((ushort)(vb.z >> 16));
    f[6] = bf2f((ushort)(vb.w & 0xffff)); f[7] = bf2f((ushort)(vb.w >> 16));

    float sum = 0.f, sq = 0.f;
    #pragma unroll
    for (int i = 0; i < 8; ++i) { sum += f[i]; sq += f[i] * f[i]; }
    #pragma unroll
    for (int o = 1; o < 64; o <<= 1) {
        sum += __shfl_xor(sum, o);
        sq  += __shfl_xor(sq, o);
    }
    float mu   = sum * (1.f / 512.f);
    float var  = sq * (1.f / 512.f) - mu * mu;
    float rstd = rsqrtf(var + 1e-5f);

    float4 r0 = *(const float4*)&res[(size_t)row * D_MODEL + c0];
    float4 r1 = *(const float4*)&res[(size_t)row * D_MODEL + c0 + 4];
    float4 g0 = *(const float4*)&g[c0],  g1 = *(const float4*)&g[c0 + 4];
    float4 b0 = *(const float4*)&bb[c0], b1 = *(const float4*)&bb[c0 + 4];

    float o8[8];
    o8[0] = r0.x + (f[0] - mu) * rstd * g0.x + b0.x;
    o8[1] = r0.y + (f[1] - mu) * rstd * g0.y + b0.y;
    o8[2] = r0.z + (f[2] - mu) * rstd * g0.z + b0.z;
    o8[3] = r0.w + (f[3] - mu) * rstd * g0.w + b0.w;
    o8[4] = r1.x + (f[4] - mu) * rstd * g1.x + b1.x;
    o8[5] = r1.y + (f[5] - mu) * rstd * g1.y + b1.y;
    o8[6] = r1.z + (f[6] - mu) * rstd * g1.z + b1.z;
    o8[7] = r1.w + (f[7] - mu) * rstd * g1.w + b1.w;

    float4* op = (float4*)&out[(size_t)row * D_MODEL + c0];
    op[0] = make_float4(o8[0], o8[1], o8[2], o8[3]);
    op[1] = make_float4(o8[4], o8[5], o8[6], o8[7]);
    if (WBF) {
        uint4 pk;
        pk.x = pack2(o8[0], o8[1]); pk.y = pack2(o8[2], o8[3]);
        pk.z = pack2(o8[4], o8[5]); pk.w = pack2(o8[6], o8[7]);
        *(uint4*)&out_bf[(size_t)row * D_MODEL + c0] = pk;
    }
}

// ---------------------------------------------------------------- launch
extern "C" void kernel_launch(void* const* d_in, const int* in_sizes, int n_in,
                              void* d_out, int out_size, void* d_ws, size_t ws_size,
                              hipStream_t stream)
{
    const float* x     = (const float*)d_in[0];
    const float* Wq    = (const float*)d_in[1];
    const float* bq    = (const float*)d_in[2];
    const float* Wk    = (const float*)d_in[3];
    const float* bk    = (const float*)d_in[4];
    const float* Wv    = (const float*)d_in[5];
    const float* bv    = (const float*)d_in[6];
    const float* Wo    = (const float*)d_in[7];
    const float* bo    = (const float*)d_in[8];
    const float* ln1_g = (const float*)d_in[9];
    const float* ln1_b = (const float*)d_in[10];
    const float* W1    = (const float*)d_in[11];
    const float* b1    = (const float*)d_in[12];
    const float* W2    = (const float*)d_in[13];
    const float* b2    = (const float*)d_in[14];
    const float* ln2_g = (const float*)d_in[15];
    const float* ln2_b = (const float*)d_in[16];

    float* ws = (float*)d_ws;
    ushort* Qg      = (ushort*)(ws);               // 8,388,608 us
    ushort* Kg      = (ushort*)(ws + 4194304);     // 8,388,608 us
    ushort* Vt      = (ushort*)(ws + 8388608);     // 8,388,608 us
    ushort* O_bf    = (ushort*)(ws + 12582912);    // 8,388,608 us
    ushort* attn_bf = (ushort*)(ws + 16777216);    // 8,388,608 us
    float*  out1    = ws + 20971520;               // 8,388,608 f32
    ushort* out1_bf = (ushort*)(ws + 29360128);    // 8,388,608 us
    ushort* x_bf    = (ushort*)(ws + 33554432);    // 8,388,608 us
    ushort* ff2_bf  = (ushort*)(ws + 37748736);    // 8,388,608 us
    ushort* WpT     = (ushort*)(ws + 41943040);    // 786,432 us
    ushort* WoT     = (ushort*)(ws + 42336256);    // 262,144 us
    ushort* W1T     = (ushort*)(ws + 42467328);    // 1,048,576 us
    ushort* W2T     = (ushort*)(ws + 42991616);    // 1,048,576 us
    float*  bp      = ws + 43515904;               // 1,536 f32
    ushort* ff1_bf  = (ushort*)ws;                 // 33,554,432 us (aliases Qg..O_bf)

    // allow 96KB dynamic LDS (idempotent; ignore errors)
    (void)hipFuncSetAttribute(
        reinterpret_cast<const void*>(&gemm_bf16_kernel<2, false>),
        hipFuncAttributeMaxDynamicSharedMemorySize, 98304);
    (void)hipFuncSetAttribute(
        reinterpret_cast<const void*>(&gemm_bf16_kernel<1, false>),
        hipFuncAttributeMaxDynamicSharedMemorySize, 98304);
    (void)hipFuncSetAttribute(
        reinterpret_cast<const void*>(&gemm_bf16_kernel<1, true>),
        hipFuncAttributeMaxDynamicSharedMemorySize, 98304);

    // fused prep: 4870 blocks
    prep_kernel<<<dim3(4870), 256, 0, stream>>>(
        x, x_bf, Wq, Wk, Wv, WpT, Wo, WoT, W1, W1T, W2, W2T, bq, bk, bv, bp);

    // QKV: x @ Wp + bp -> Qg/Kg natural, Vt transposed. grid 12*64=768
    gemm_bf16_kernel<2, false><<<dim3(768), 512, 98304, stream>>>(
        x_bf, WpT, bp, nullptr, Qg, Kg, Vt, NROWS, 1536, 512, 12);

    // attention -> O_bf
    attn_kernel<<<dim3(256, 8), 256, 0, stream>>>(Qg, Kg, Vt, O_bf);

    // attn = O @ Wo + bo -> bf16. grid 4*64=256
    gemm_bf16_kernel<1, false><<<dim3(256), 512, 98304, stream>>>(
        O_bf, WoT, bo, attn_bf, nullptr, nullptr, nullptr, NROWS, 512, 512, 4);

    // out1 = x + LN(attn); + bf16 copy
    ln_res_kernel<true><<<dim3(NROWS / 4), 256, 0, stream>>>(
        attn_bf, x, ln1_g, ln1_b, out1, out1_bf);

    // ff1 = relu(out1 @ W1 + b1) -> bf16. grid 16*64=1024
    gemm_bf16_kernel<1, true><<<dim3(1024), 512, 98304, stream>>>(
        out1_bf, W1T, b1, ff1_bf, nullptr, nullptr, nullptr, NROWS, 2048, 512, 16);

    // ff2 = ff1 @ W2 + b2 -> bf16. grid 4*64=256, T=32
    gemm_bf16_kernel<1, false><<<dim3(256), 512, 98304, stream>>>(
        ff1_bf, W2T, b2, ff2_bf, nullptr, nullptr, nullptr, NROWS, 512, 2048, 4);

    // out = out1 + LN(ff2)
    ln_res_kernel<false><<<dim3(NROWS / 4), 256, 0, stream>>>(
        ff2_bf, out1, ln2_g, ln2_b, (float*)d_out, nullptr);
}